// Round 1
// baseline (555.369 us; speedup 1.0000x reference)
//
#include <hip/hip_runtime.h>
#include <hip/hip_bf16.h>

// out = (adj @ (item_emb @ W)) / (rowsum(adj) + eps)
// adj: [16384][32768] f32, item_emb: [32768][64] f32, W: [64][64] f32
// Strategy: precompute P = item_emb@W (bf16, fragment-packed in d_ws),
// then one streaming pass over adj: fp32 load -> deg accum + bf16 convert ->
// v_mfma_f32_16x16x16_bf16, 16 rows per wave, 1024 waves, no LDS/barriers.

#define M 16384
#define K 32768
#define NOUT 64
#define EMB 64
#define EPSV 1e-8f

typedef __attribute__((ext_vector_type(4))) float f32x4;
typedef __attribute__((ext_vector_type(4))) short s16x4;
typedef __attribute__((ext_vector_type(4))) unsigned short u16x4;
typedef __attribute__((ext_vector_type(8))) unsigned short u16x8;

static __device__ __forceinline__ unsigned short f2bf(float f) {
    // round-to-nearest-even fp32 -> bf16 (inputs are finite, no NaN handling needed)
    unsigned int u = __float_as_uint(f);
    u += 0x7fffu + ((u >> 16) & 1u);
    return (unsigned short)(u >> 16);
}

// ---------------------------------------------------------------------------
// Kernel 1: P = item_emb @ W, stored bf16 in MFMA-B-fragment-packed order.
// Packed layout (16B granules): granule index = (kc*8 + nt*2 + kp)*64 + lane,
// where for element P[k][n]: kc=k/64, ksub=(k/16)%4, kp=ksub/2, g=(k/4)%3..,
// lane = g*16 + (n%16), nt = n/16; the 16B granule holds ksub=2kp (bytes 0..7)
// and ksub=2kp+1 (bytes 8..15), each 4 consecutive-k bf16 values.
// ---------------------------------------------------------------------------
__global__ __launch_bounds__(256) void pack_p_kernel(const float* __restrict__ emb,
                                                     const float* __restrict__ W,
                                                     unsigned short* __restrict__ ppack) {
    int tid = blockIdx.x * 256 + threadIdx.x;   // 0 .. 524287
    int kq  = tid >> 6;                          // k-quad index, 0..8191 (k = 4*kq)
    int n   = tid & 63;

    const f32x4* emb4 = (const f32x4*)(emb + (size_t)(kq * 4) * EMB);
    float acc0 = 0.f, acc1 = 0.f, acc2 = 0.f, acc3 = 0.f;
#pragma unroll
    for (int e4 = 0; e4 < 16; ++e4) {
        float w0 = W[(4 * e4 + 0) * NOUT + n];
        float w1 = W[(4 * e4 + 1) * NOUT + n];
        float w2 = W[(4 * e4 + 2) * NOUT + n];
        float w3 = W[(4 * e4 + 3) * NOUT + n];
        f32x4 e0 = emb4[0 * 16 + e4];
        f32x4 e1 = emb4[1 * 16 + e4];
        f32x4 e2 = emb4[2 * 16 + e4];
        f32x4 e3 = emb4[3 * 16 + e4];
        acc0 += e0.x * w0 + e0.y * w1 + e0.z * w2 + e0.w * w3;
        acc1 += e1.x * w0 + e1.y * w1 + e1.z * w2 + e1.w * w3;
        acc2 += e2.x * w0 + e2.y * w1 + e2.z * w2 + e2.w * w3;
        acc3 += e3.x * w0 + e3.y * w1 + e3.z * w2 + e3.w * w3;
    }

    int kc   = kq >> 4;
    int ksub = (kq >> 2) & 3;
    int g    = kq & 3;
    int nt   = n >> 4;
    int r    = n & 15;
    int lane = g * 16 + r;
    size_t gran = (size_t)(kc * 8 + nt * 2 + (ksub >> 1)) * 64 + lane; // 16B units
    u16x4 v = { f2bf(acc0), f2bf(acc1), f2bf(acc2), f2bf(acc3) };
    *((u16x4*)ppack + gran * 2 + (ksub & 1)) = v;
}

// ---------------------------------------------------------------------------
// Kernel 2: streaming adj pass. One wave = 16 output rows x 64 cols.
// Per K-chunk (64): each lane loads 4x float4 of adj (its own A fragments),
// 8x 16B of packed P (B fragments), 16 MFMA. Double-buffered 2 chunks deep.
// ---------------------------------------------------------------------------
__global__ __launch_bounds__(256) void meanconv_main(const float* __restrict__ adj,
                                                     const unsigned short* __restrict__ ppack,
                                                     float* __restrict__ out) {
    const int lane = threadIdx.x & 63;
    const int wave = (blockIdx.x * 256 + threadIdx.x) >> 6;  // 0..1023
    const int r = lane & 15;
    const int g = lane >> 4;
    const int row_base = wave * 16;

    const float* arow = adj + (size_t)(row_base + r) * K + g * 4;
    const u16x8* bbase = (const u16x8*)ppack + lane;  // 16B granules

    f32x4 acc[4];
#pragma unroll
    for (int t = 0; t < 4; ++t) acc[t] = (f32x4)0.0f;
    float dsum = 0.0f;

    f32x4 aA[4], aB[4];
    u16x8 bA[8], bB[8];

    // prologue: chunks 0 and 1
#pragma unroll
    for (int s = 0; s < 4; ++s)
        aA[s] = __builtin_nontemporal_load((const f32x4*)(arow + 0 * 64 + s * 16));
#pragma unroll
    for (int q = 0; q < 8; ++q) bA[q] = bbase[((size_t)0 * 8 + q) * 64];
#pragma unroll
    for (int s = 0; s < 4; ++s)
        aB[s] = __builtin_nontemporal_load((const f32x4*)(arow + 1 * 64 + s * 16));
#pragma unroll
    for (int q = 0; q < 8; ++q) bB[q] = bbase[((size_t)1 * 8 + q) * 64];

    for (int kc = 0; kc < K / 64; kc += 2) {
        // ---- compute chunk kc (buffers A) ----
#pragma unroll
        for (int s = 0; s < 4; ++s) {
            f32x4 av = aA[s];
            dsum += av.x + av.y + av.z + av.w;
            s16x4 af = { (short)f2bf(av.x), (short)f2bf(av.y),
                         (short)f2bf(av.z), (short)f2bf(av.w) };
#pragma unroll
            for (int nt = 0; nt < 4; ++nt) {
                u16x8 bb = bA[nt * 2 + (s >> 1)];
                const int h = (s & 1) * 4;
                s16x4 bfq = { (short)bb[h + 0], (short)bb[h + 1],
                              (short)bb[h + 2], (short)bb[h + 3] };
                acc[nt] = __builtin_amdgcn_mfma_f32_16x16x16bf16_1k(af, bfq, acc[nt], 0, 0, 0);
            }
        }
        // refill A with chunk kc+2
        if (kc + 2 < K / 64) {
#pragma unroll
            for (int s = 0; s < 4; ++s)
                aA[s] = __builtin_nontemporal_load(
                    (const f32x4*)(arow + (size_t)(kc + 2) * 64 + s * 16));
#pragma unroll
            for (int q = 0; q < 8; ++q) bA[q] = bbase[((size_t)(kc + 2) * 8 + q) * 64];
        }
        // ---- compute chunk kc+1 (buffers B) ----
#pragma unroll
        for (int s = 0; s < 4; ++s) {
            f32x4 av = aB[s];
            dsum += av.x + av.y + av.z + av.w;
            s16x4 af = { (short)f2bf(av.x), (short)f2bf(av.y),
                         (short)f2bf(av.z), (short)f2bf(av.w) };
#pragma unroll
            for (int nt = 0; nt < 4; ++nt) {
                u16x8 bb = bB[nt * 2 + (s >> 1)];
                const int h = (s & 1) * 4;
                s16x4 bfq = { (short)bb[h + 0], (short)bb[h + 1],
                              (short)bb[h + 2], (short)bb[h + 3] };
                acc[nt] = __builtin_amdgcn_mfma_f32_16x16x16bf16_1k(af, bfq, acc[nt], 0, 0, 0);
            }
        }
        // refill B with chunk kc+3
        if (kc + 3 < K / 64) {
#pragma unroll
            for (int s = 0; s < 4; ++s)
                aB[s] = __builtin_nontemporal_load(
                    (const f32x4*)(arow + (size_t)(kc + 3) * 64 + s * 16));
#pragma unroll
            for (int q = 0; q < 8; ++q) bB[q] = bbase[((size_t)(kc + 3) * 8 + q) * 64];
        }
    }

    // deg: each lane holds partial row-sum of row r (its g-quarter of columns).
    float deg = dsum;
    deg += __shfl_xor(deg, 16);
    deg += __shfl_xor(deg, 32);
    // acc[nt][i] = D[row 4g+i][col nt*16+r]; need deg of row 4g+i -> lane (4g+i)
    float* orow = out + (size_t)row_base * NOUT + r;
#pragma unroll
    for (int i = 0; i < 4; ++i) {
        float d = __shfl(deg, g * 4 + i);
        float rd = 1.0f / (d + EPSV);
#pragma unroll
        for (int nt = 0; nt < 4; ++nt) {
            orow[(g * 4 + i) * NOUT + nt * 16] = acc[nt][i] * rd;
        }
    }
}

extern "C" void kernel_launch(void* const* d_in, const int* in_sizes, int n_in,
                              void* d_out, int out_size, void* d_ws, size_t ws_size,
                              hipStream_t stream) {
    const float* adj = (const float*)d_in[0];
    const float* emb = (const float*)d_in[1];
    const float* W   = (const float*)d_in[2];
    float* out = (float*)d_out;
    unsigned short* ppack = (unsigned short*)d_ws;  // 4 MB bf16 packed P

    hipLaunchKernelGGL(pack_p_kernel, dim3((K / 4 * NOUT) / 256), dim3(256), 0, stream,
                       emb, W, ppack);
    hipLaunchKernelGGL(meanconv_main, dim3(M / 16 / 4), dim3(256), 0, stream,
                       adj, ppack, out);
}